// Round 15
// baseline (151.453 us; speedup 1.0000x reference)
//
#include <hip/hip_runtime.h>
#include <cstdint>

typedef unsigned int uint;
typedef unsigned short ushort;
typedef __attribute__((ext_vector_type(8))) short bf16x8;
typedef __attribute__((ext_vector_type(4))) float f32x4;

// ---------- helpers ----------
__device__ __forceinline__ ushort f2b(float f) {
  union { float f; uint u; } v; v.f = f;
  uint u = v.u;
  uint r = (u + 0x7FFFu + ((u >> 16) & 1u)) >> 16;   // RNE
  return (ushort)r;
}
__device__ __forceinline__ float b2f(ushort h) {
  union { uint u; float f; } v; v.u = ((uint)h) << 16; return v.f;
}

// ---------- K_prepA: SK (blocks 0..255) + kh/vh (blocks 256..383); no LDS ----------
__global__ __launch_bounds__(256) void k_prepA(
    const float* __restrict__ know, const float* __restrict__ eslots,
    const float* __restrict__ Ek, const float* __restrict__ Ev, const float* __restrict__ Sin,
    ushort* __restrict__ Wcat, float* __restrict__ kh, float* __restrict__ vh)
{
  int bid = blockIdx.x;
  int tid = threadIdx.x;
  int lane = tid & 63, wv = tid >> 6;

  if (bid < 256) {
    int k = bid * 2 + (wv >> 1);         // [0,512)
    int s0 = (wv & 1) * 32;
    const float* sp = Sin + (size_t)k * 512 + lane * 8;
    float4 s1 = *(const float4*)&sp[0];
    float4 s2 = *(const float4*)&sp[4];
    #pragma unroll 4
    for (int si = 0; si < 32; ++si) {
      int s = s0 + si;
      const float* kp = know + (size_t)s * 512 + lane * 8;
      float4 k1 = *(const float4*)&kp[0];
      float4 k2 = *(const float4*)&kp[4];
      float part = s1.x * k1.x + s1.y * k1.y + s1.z * k1.z + s1.w * k1.w
                 + s2.x * k2.x + s2.y * k2.y + s2.z * k2.z + s2.w * k2.w;
      #pragma unroll
      for (int o = 32; o; o >>= 1) part += __shfl_xor(part, o);
      if (lane == 0) Wcat[(640 + s) * 512 + k] = f2b(part * 0.04419417382415922f); // 1/sqrt(512)
    }
    return;
  }
  {
    int t = (bid - 256) * 256 + tid;     // [0,32768)
    int isv = (t >= 16384);
    int o = t & 16383; int s = o >> 9, j = o & 511;
    const float* W = isv ? Ev : Ek;
    const float* es = eslots + (size_t)s * 512;
    float a0 = 0.f, a1 = 0.f, a2 = 0.f, a3 = 0.f;
    #pragma unroll 8
    for (int d = 0; d < 512; d += 4) {
      a0 += es[d + 0] * W[(size_t)(d + 0) * 512 + j];
      a1 += es[d + 1] * W[(size_t)(d + 1) * 512 + j];
      a2 += es[d + 2] * W[(size_t)(d + 2) * 512 + j];
      a3 += es[d + 3] * W[(size_t)(d + 3) * 512 + j];
    }
    float acc = (a0 + a1) + (a2 + a3);
    (isv ? vh : kh)[(size_t)s * 512 + j] = acc;
  }
}

// ---------- K_prepB: EK (0..255) + VO (256..511) + transposes (512..807) + X16 (808..935) + know16 (936..951) ----------
__global__ __launch_bounds__(256) void k_prepB(
    const float* __restrict__ x, const float* __restrict__ Wv, const float* __restrict__ Sg,
    const float* __restrict__ C1w, const float* __restrict__ Wq, const float* __restrict__ Wk,
    const float* __restrict__ Wf, const float* __restrict__ Wo, const float* __restrict__ So,
    const float* __restrict__ Eq, const float* __restrict__ Eo, const float* __restrict__ know,
    const float* __restrict__ kh, const float* __restrict__ vh,
    ushort* __restrict__ X16, ushort* __restrict__ Wcat, ushort* __restrict__ Wfin,
    ushort* __restrict__ know16)
{
  __shared__ __align__(16) float pool[4160];
  int bid = blockIdx.x;
  int tid = threadIdx.x;
  int lane = tid & 63, wv = tid >> 6;

  if (bid < 256) {
    int gw = bid * 4 + wv;               // [0,1024)
    #pragma unroll
    for (int pp = 0; pp < 2; ++pp) {
      int pair = gw * 2 + pp;            // [0,2048) = (k,h)
      int k = pair >> 2, h = pair & 3;
      const float* ep = Eq + (size_t)k * 512 + h * 128 + lane * 2;
      float e0 = ep[0], e1 = ep[1];
      #pragma unroll 4
      for (int s = 0; s < 32; ++s) {
        const float* kp = kh + (size_t)s * 512 + h * 128 + lane * 2;
        float part = e0 * kp[0] + e1 * kp[1];
        #pragma unroll
        for (int o = 32; o; o >>= 1) part += __shfl_xor(part, o);
        if (lane == 0) Wcat[(512 + h * 32 + s) * 512 + k] = f2b(part * 0.08838834764831845f);
      }
    }
    return;
  }
  if (bid < 512) {
    int o = (bid - 256) * 256 + tid;     // [0,65536)
    int hs = o >> 9, j = o & 511;
    int h = hs >> 5, s = hs & 31;
    const float* vhp = vh + (size_t)s * 512 + h * 128;
    float acc = 0.f;
    #pragma unroll 16
    for (int e = 0; e < 128; ++e) acc += vhp[e] * Eo[(size_t)(h * 128 + e) * 512 + j];
    Wfin[(size_t)j * 1152 + 1024 + hs] = f2b(acc);
    return;
  }
  if (bid < 808) {
    #define Tm(a,b) pool[(a) * 65 + (b)]
    int tt = bid - 512;
    const float* src; ushort* dst; int sld, dld, Nt, drow, dcol;
    if (tt < 64)       {           src = Wv;  dst = Wcat; sld = 512; dld = 512;  Nt = 8; drow = 0;    dcol = 0;   }
    else if (tt < 128) { tt -= 64; src = Sg;  dst = Wcat; sld = 512; dld = 512;  Nt = 8; drow = 704;  dcol = 0;   }
    else if (tt < 144) { tt -= 128; src = C1w; dst = Wcat; sld = 128; dld = 512; Nt = 2; drow = 1216; dcol = 0;   }
    else if (tt < 152) { tt -= 144; src = Wq;  dst = Wcat; sld = 64;  dld = 512; Nt = 1; drow = 1344; dcol = 0;   }
    else if (tt < 160) { tt -= 152; src = Wk;  dst = Wcat; sld = 64;  dld = 512; Nt = 1; drow = 1408; dcol = 0;   }
    else if (tt < 168) { tt -= 160; src = Wf;  dst = Wcat; sld = 64;  dld = 512; Nt = 1; drow = 1472; dcol = 0;   }
    else if (tt < 232) { tt -= 168; src = Wo;  dst = Wfin; sld = 512; dld = 1152; Nt = 8; drow = 0;   dcol = 0;   }
    else               { tt -= 232; src = So;  dst = Wfin; sld = 512; dld = 1152; Nt = 8; drow = 0;   dcol = 512; }
    int tk = tt / Nt, tn = tt % Nt;
    int k0 = tk * 64, n0 = tn * 64;
    int r = tid >> 4, c = (tid & 15) * 4;
    #pragma unroll
    for (int p = 0; p < 4; ++p) {
      int kk = p * 16 + r;
      float4 v = *(const float4*)&src[(size_t)(k0 + kk) * sld + n0 + c];
      Tm(c + 0, kk) = v.x; Tm(c + 1, kk) = v.y; Tm(c + 2, kk) = v.z; Tm(c + 3, kk) = v.w;
    }
    __syncthreads();
    int n = tid >> 2, kc = (tid & 3) * 16;
    uint u[8];
    #pragma unroll
    for (int j = 0; j < 8; ++j) {
      ushort lo = f2b(Tm(n, kc + 2 * j));
      ushort hi = f2b(Tm(n, kc + 2 * j + 1));
      u[j] = (uint)lo | ((uint)hi << 16);
    }
    size_t off = (size_t)(drow + n0 + n) * dld + dcol + k0 + kc;
    uint4 o1; o1.x = u[0]; o1.y = u[1]; o1.z = u[2]; o1.w = u[3];
    uint4 o2; o2.x = u[4]; o2.y = u[5]; o2.z = u[6]; o2.w = u[7];
    *(uint4*)&dst[off] = o1;
    *(uint4*)&dst[off + 8] = o2;
    #undef Tm
    return;
  }
  if (bid < 936) {
    int base = (bid - 808) * 256 + tid;
    #pragma unroll
    for (int it = 0; it < 8; ++it) {
      int t = base + it * 32768;
      float4 xv = *(const float4*)&x[(size_t)t * 4];
      uint2 o;
      o.x = (uint)f2b(xv.x) | ((uint)f2b(xv.y) << 16);
      o.y = (uint)f2b(xv.z) | ((uint)f2b(xv.w) << 16);
      *(uint2*)&X16[(size_t)t * 4] = o;
    }
    return;
  }
  {
    int t = (bid - 936) * 256 + tid;
    #pragma unroll
    for (int j = 0; j < 2; ++j) {
      float4 v = *(const float4*)&know[(size_t)t * 8 + j * 4];
      uint2 o;
      o.x = (uint)f2b(v.x) | ((uint)f2b(v.y) << 16);
      o.y = (uint)f2b(v.z) | ((uint)f2b(v.w) << 16);
      *(uint2*)&know16[(size_t)t * 8 + j * 4] = o;
    }
  }
}

// ---------- GEMM1: 64x128 tile + fused epilogues + s16 emit (forget-col blocks) ----------
__global__ __launch_bounds__(256) void k_gemm1(
    const ushort* __restrict__ A, const ushort* __restrict__ Bw, float* __restrict__ C,
    const float* __restrict__ sgb, const float* __restrict__ c1b, const float* __restrict__ bfb,
    float* __restrict__ s16)
{
  __shared__ __align__(16) char poolraw[24832];   // As(4KB) + Bs(8KB); reused as sf[64][48+...]
  ushort* As = (ushort*)poolraw;                  // 64*32
  ushort* Bs = As + 2048;                         // 128*32
  float* sf = (float*)poolraw;                    // 64 rows x 65 cols (16.6KB < 24.25KB)
  int tid = threadIdx.x;
  int lane = tid & 63, wv = tid >> 6;
  int wm = (wv & 1) * 32, wn = (wv >> 1) * 64;
  int lr = lane & 15, lk = lane >> 4;
  int m0 = blockIdx.y * 64, n0 = blockIdx.x * 128;
  f32x4 zero4 = {0.f, 0.f, 0.f, 0.f};
  f32x4 acc[2][4];
  #pragma unroll
  for (int a = 0; a < 2; ++a)
    #pragma unroll
    for (int b = 0; b < 4; ++b) acc[a][b] = zero4;
  for (int kt = 0; kt < 16; ++kt) {
    int k0 = kt * 32;
    {
      int p = tid, row = p >> 2, cc = p & 3;
      int cs = cc ^ ((row >> 1) & 3);
      *(uint4*)&As[p * 8] = *(const uint4*)&A[(size_t)(m0 + row) * 512 + k0 + cs * 8];
    }
    #pragma unroll
    for (int i = 0; i < 2; ++i) {
      int p = i * 256 + tid, row = p >> 2, cc = p & 3;
      int cs = cc ^ ((row >> 1) & 3);
      *(uint4*)&Bs[p * 8] = *(const uint4*)&Bw[(size_t)(n0 + row) * 512 + k0 + cs * 8];
    }
    __syncthreads();
    bf16x8 af[2], bfv[4];
    #pragma unroll
    for (int mi = 0; mi < 2; ++mi) {
      int row = wm + mi * 16 + lr;
      int cc = lk ^ ((row >> 1) & 3);
      af[mi] = *(bf16x8*)&As[row * 32 + cc * 8];
    }
    #pragma unroll
    for (int ni = 0; ni < 4; ++ni) {
      int row = wn + ni * 16 + lr;
      int cc = lk ^ ((row >> 1) & 3);
      bfv[ni] = *(bf16x8*)&Bs[row * 32 + cc * 8];
    }
    #pragma unroll
    for (int mi = 0; mi < 2; ++mi)
      #pragma unroll
      for (int ni = 0; ni < 4; ++ni)
        acc[mi][ni] = __builtin_amdgcn_mfma_f32_16x16x32_bf16(af[mi], bfv[ni], acc[mi][ni], 0, 0, 0);
    __syncthreads();
  }
  int isFblk = (n0 == 1408);
  #pragma unroll
  for (int mi = 0; mi < 2; ++mi) {
    #pragma unroll
    for (int ni = 0; ni < 4; ++ni) {
      int col = n0 + wn + ni * 16 + lr;
      #pragma unroll
      for (int r = 0; r < 4; ++r) {
        int rowb = m0 + wm + mi * 16 + lk * 4 + r;
        float v = acc[mi][ni][r];
        if (col >= 704) {
          if (col < 1216) { v = 1.f / (1.f + __expf(-(v + sgb[col - 704]))); }
          else if (col < 1344) { float tt = v + c1b[col - 1216]; v = tt / (1.f + __expf(-tt)); }
          else if (col < 1408) { float e = (v > 0.f) ? v : (__expf(v) - 1.f); v = (e + 1.f) * 0.125f; }
          else if (col < 1472) { float e = (v > 0.f) ? v : (__expf(v) - 1.f); v = e + 1.f; }
          else { float logit = v + bfb[col - 1472];
                 float s = 1.f / (1.f + expf(-logit));
                 v = logf(fmaxf(s, 1e-6f));
                 if (isFblk) sf[(wm + mi * 16 + lk * 4 + r) * 65 + (col - 1472)] = v; }
        }
        C[(size_t)rowb * 1536 + col] = v;
      }
    }
  }
  if (isFblk) {
    __syncthreads();
    // reduce 16-row groups: thread (g = tid>>6, m = tid&63)
    int g = tid >> 6, m = tid & 63;
    float s = 0.f;
    #pragma unroll
    for (int i = 0; i < 16; ++i) s += sf[(g * 16 + i) * 65 + m];
    s16[(size_t)(blockIdx.y * 4 + g) * 64 + m] = s;
  }
}

// ---------- GEMM2 ----------
__global__ __launch_bounds__(256) void k_gemm2(
    const ushort* __restrict__ A, const ushort* __restrict__ Bw, float* __restrict__ C)
{
  __shared__ __align__(16) ushort As[64 * 32];
  __shared__ __align__(16) ushort Bs[64 * 32];
  int tid = threadIdx.x;
  int lane = tid & 63, wv = tid >> 6;
  int wm = (wv & 1) * 32, wn = (wv >> 1) * 32;
  int lr = lane & 15, lk = lane >> 4;
  int m0 = blockIdx.y * 64, n0 = blockIdx.x * 64;
  f32x4 zero4 = {0.f, 0.f, 0.f, 0.f};
  f32x4 acc[2][2];
  #pragma unroll
  for (int a = 0; a < 2; ++a)
    #pragma unroll
    for (int b = 0; b < 2; ++b) acc[a][b] = zero4;
  for (int kt = 0; kt < 36; ++kt) {
    int k0 = kt * 32;
    {
      int p = tid, row = p >> 2, cc = p & 3;
      int cs = cc ^ ((row >> 1) & 3);
      *(uint4*)&As[p * 8] = *(const uint4*)&A[(size_t)(m0 + row) * 1152 + k0 + cs * 8];
      *(uint4*)&Bs[p * 8] = *(const uint4*)&Bw[(size_t)(n0 + row) * 1152 + k0 + cs * 8];
    }
    __syncthreads();
    bf16x8 af[2], bfv[2];
    #pragma unroll
    for (int mi = 0; mi < 2; ++mi) {
      int row = wm + mi * 16 + lr;
      int cc = lk ^ ((row >> 1) & 3);
      af[mi] = *(bf16x8*)&As[row * 32 + cc * 8];
    }
    #pragma unroll
    for (int ni = 0; ni < 2; ++ni) {
      int row = wn + ni * 16 + lr;
      int cc = lk ^ ((row >> 1) & 3);
      bfv[ni] = *(bf16x8*)&Bs[row * 32 + cc * 8];
    }
    #pragma unroll
    for (int mi = 0; mi < 2; ++mi)
      #pragma unroll
      for (int ni = 0; ni < 2; ++ni)
        acc[mi][ni] = __builtin_amdgcn_mfma_f32_16x16x32_bf16(af[mi], bfv[ni], acc[mi][ni], 0, 0, 0);
    __syncthreads();
  }
  #pragma unroll
  for (int mi = 0; mi < 2; ++mi) {
    #pragma unroll
    for (int ni = 0; ni < 2; ++ni) {
      int col = n0 + wn + ni * 16 + lr;
      #pragma unroll
      for (int r = 0; r < 4; ++r) {
        int rowb = m0 + wm + mi * 16 + lk * 4 + r;
        C[(size_t)rowb * 512 + col] = acc[mi][ni][r];
      }
    }
  }
}

// ---------- K_scanA: inline gates (from s16 + P) + per-chunk partial states ----------
// grid 512: dt = bid&7, c = (bid>>3)&31, b = bid>>8
__global__ __launch_bounds__(256) void k_scanA(
    const float* __restrict__ P, const float* __restrict__ s16,
    float* __restrict__ Send, float* __restrict__ zSend)
{
  __shared__ __align__(16) float lfS[32 * 64];
  __shared__ __align__(16) float kS[32 * 64];    // k, then cn in place
  __shared__ __align__(16) float vS[16 * 64];
  __shared__ float bpP[4][64];
  __shared__ float zsP[2][64];
  int tid = threadIdx.x;
  int bid = blockIdx.x;
  int dt = bid & 7, c = (bid >> 3) & 31, b = bid >> 8;
  int rb0 = b * 1024 + c * 32;
  #pragma unroll
  for (int it = 0; it < 2; ++it) {
    int p = it * 256 + tid;
    int row = p >> 4, c4f = (p & 15) * 4;
    *(float4*)&lfS[row * 64 + c4f] = *(const float4*)&P[(size_t)(rb0 + row) * 1536 + 1472 + c4f];
    *(float4*)&kS[row * 64 + c4f] = *(const float4*)&P[(size_t)(rb0 + row) * 1536 + 1408 + c4f];
  }
  // base prefix over 16-row groups g < c*2 (within batch b)
  {
    int m = tid & 63, gq = tid >> 6;
    float part = 0.f;
    for (int g = gq; g < c * 2; g += 4) part += s16[(size_t)(b * 64 + g) * 64 + m];
    bpP[gq][m] = part;
  }
  __syncthreads();
  // gate walk: threads (m 64, q 2)
  if (tid < 128) {
    int mq = tid & 63, q = tid >> 6;
    float run = bpP[0][mq] + bpP[1][mq] + bpP[2][mq] + bpP[3][mq];
    if (q == 1) run += s16[(size_t)(b * 64 + c * 2) * 64 + mq];
    float zs = 0.f;
    #pragma unroll
    for (int i = 0; i < 16; ++i) {
      int row = q * 16 + i;
      run += lfS[row * 64 + mq];
      float lf = fminf(fmaxf(run, -20.f), 20.f);
      float cv = __expf(-lf) * kS[row * 64 + mq];
      kS[row * 64 + mq] = cv;
      zs += cv;
    }
    zsP[q][mq] = zs;
  }
  __syncthreads();
  if (dt == 0 && tid < 64)
    zSend[(size_t)(b * 32 + c) * 64 + tid] = zsP[0][tid] + zsP[1][tid];
  // Send accumulate
  int mg = tid >> 4, dl = tid & 15;
  float4 acc[4];
  #pragma unroll
  for (int i = 0; i < 4; ++i) acc[i] = make_float4(0.f, 0.f, 0.f, 0.f);
  for (int ig = 0; ig < 2; ++ig) {
    int rb = rb0 + ig * 16;
    int row = tid >> 4, c4f = (tid & 15) * 4;
    *(float4*)&vS[row * 64 + c4f] = *(const float4*)&P[(size_t)(rb + row) * 1536 + dt * 64 + c4f];
    __syncthreads();
    #pragma unroll 4
    for (int i = 0; i < 16; ++i) {
      float4 vv = *(float4*)&vS[i * 64 + dl * 4];
      float4 cm = *(float4*)&kS[(ig * 16 + i) * 64 + mg * 4];
      acc[0].x += cm.x * vv.x; acc[0].y += cm.x * vv.y; acc[0].z += cm.x * vv.z; acc[0].w += cm.x * vv.w;
      acc[1].x += cm.y * vv.x; acc[1].y += cm.y * vv.y; acc[1].z += cm.y * vv.z; acc[1].w += cm.y * vv.w;
      acc[2].x += cm.z * vv.x; acc[2].y += cm.z * vv.y; acc[2].z += cm.z * vv.z; acc[2].w += cm.z * vv.w;
      acc[3].x += cm.w * vv.x; acc[3].y += cm.w * vv.y; acc[3].z += cm.w * vv.z; acc[3].w += cm.w * vv.w;
    }
    __syncthreads();
  }
  #pragma unroll
  for (int mi = 0; mi < 4; ++mi) {
    int m = mg * 4 + mi;
    *(float4*)&Send[(size_t)((b * 32 + c) * 64 + m) * 512 + dt * 64 + dl * 4] = acc[mi];
  }
}

// ---------- K_scanB: exclusive chunk prefix over 32 chunks ----------
__global__ __launch_bounds__(256) void k_scanB(const float* __restrict__ Send, float* __restrict__ carry)
{
  int t = blockIdx.x * 256 + threadIdx.x;   // 65536
  int d = t & 511, m = (t >> 9) & 63, b = t >> 15;
  float run = 0.f;
  #pragma unroll 8
  for (int c = 0; c < 32; ++c) {
    size_t idx = (size_t)((b * 32 + c) * 64 + m) * 512 + d;
    carry[idx] = run;
    run += Send[idx];
  }
}

// ---------- K_scanC: inline gates + in-chunk scan -> num, den (dt==0) ----------
__global__ __launch_bounds__(256) void k_scanC(
    const float* __restrict__ P, const float* __restrict__ s16,
    const float* __restrict__ carry, const float* __restrict__ zSend,
    float* __restrict__ num, float* __restrict__ den)
{
  __shared__ __align__(16) float lfS[32 * 64];
  __shared__ __align__(16) float cnS[32 * 64];   // k -> cn
  __shared__ __align__(16) float qS[32 * 64];    // q -> qe
  __shared__ __align__(16) float vS[16 * 64];
  __shared__ float bpP[4][64];
  int tid = threadIdx.x;
  int bid = blockIdx.x;
  int dt = bid & 7, c = (bid >> 3) & 31, b = bid >> 8;
  int rb0 = b * 1024 + c * 32;
  #pragma unroll
  for (int it = 0; it < 2; ++it) {
    int p = it * 256 + tid;
    int row = p >> 4, c4f = (p & 15) * 4;
    *(float4*)&lfS[row * 64 + c4f] = *(const float4*)&P[(size_t)(rb0 + row) * 1536 + 1472 + c4f];
    *(float4*)&cnS[row * 64 + c4f] = *(const float4*)&P[(size_t)(rb0 + row) * 1536 + 1408 + c4f];
    *(float4*)&qS[row * 64 + c4f] = *(const float4*)&P[(size_t)(rb0 + row) * 1536 + 1344 + c4f];
  }
  {
    int m = tid & 63, gq = tid >> 6;
    float part = 0.f;
    for (int g = gq; g < c * 2; g += 4) part += s16[(size_t)(b * 64 + g) * 64 + m];
    bpP[gq][m] = part;
  }
  __syncthreads();
  if (tid < 128) {
    int mq = tid & 63, q = tid >> 6;
    float run = bpP[0][mq] + bpP[1][mq] + bpP[2][mq] + bpP[3][mq];
    if (q == 1) run += s16[(size_t)(b * 64 + c * 2) * 64 + mq];
    #pragma unroll
    for (int i = 0; i < 16; ++i) {
      int row = q * 16 + i;
      run += lfS[row * 64 + mq];
      float lf = fminf(fmaxf(run, -20.f), 20.f);
      float en = __expf(-lf), ep = __expf(lf);
      cnS[row * 64 + mq] = en * cnS[row * 64 + mq];
      qS[row * 64 + mq] = qS[row * 64 + mq] * ep;
    }
  }
  __syncthreads();
  int mg = tid & 3, dl = tid >> 2;
  int d = dt * 64 + dl;
  float S[16];
  float z16[16];
  #pragma unroll
  for (int mi = 0; mi < 16; ++mi) {
    S[mi] = carry[(size_t)((b * 32 + c) * 64 + mg * 16 + mi) * 512 + d];
    z16[mi] = 0.f;
  }
  if (dt == 0) {
    for (int j = 0; j < c; ++j) {
      size_t zb = (size_t)(b * 32 + j) * 64 + mg * 16;
      #pragma unroll
      for (int mi = 0; mi < 16; ++mi) z16[mi] += zSend[zb + mi];
    }
  }
  for (int ig = 0; ig < 2; ++ig) {
    int rb = rb0 + ig * 16;
    int row = tid >> 4, c4f = (tid & 15) * 4;
    *(float4*)&vS[row * 64 + c4f] = *(const float4*)&P[(size_t)(rb + row) * 1536 + dt * 64 + c4f];
    __syncthreads();
    for (int i = 0; i < 16; ++i) {
      int ii = ig * 16 + i;
      float vv = vS[i * 64 + dl];
      float p = 0.f;
      float dp = 0.f;
      #pragma unroll
      for (int j = 0; j < 4; ++j) {
        float4 c4 = *(float4*)&cnS[ii * 64 + mg * 16 + j * 4];
        float4 q4 = *(float4*)&qS[ii * 64 + mg * 16 + j * 4];
        S[j * 4 + 0] += c4.x * vv; p += q4.x * S[j * 4 + 0];
        S[j * 4 + 1] += c4.y * vv; p += q4.y * S[j * 4 + 1];
        S[j * 4 + 2] += c4.z * vv; p += q4.z * S[j * 4 + 2];
        S[j * 4 + 3] += c4.w * vv; p += q4.w * S[j * 4 + 3];
        if (dt == 0) {
          z16[j * 4 + 0] += c4.x; dp += q4.x * z16[j * 4 + 0];
          z16[j * 4 + 1] += c4.y; dp += q4.y * z16[j * 4 + 1];
          z16[j * 4 + 2] += c4.z; dp += q4.z * z16[j * 4 + 2];
          z16[j * 4 + 3] += c4.w; dp += q4.w * z16[j * 4 + 3];
        }
      }
      p += __shfl_xor(p, 1);
      p += __shfl_xor(p, 2);
      if (mg == 0) num[(size_t)(rb0 + ii) * 512 + d] = p;
      if (dt == 0) {
        dp += __shfl_xor(dp, 1);
        dp += __shfl_xor(dp, 2);
        if (mg == 0 && dl == 0) den[rb0 + ii] = dp;
      }
    }
    __syncthreads();
  }
}

// ---------- K_post: ctrl + ln + esoft + sem fused (4 rows/block, wave=row) ----------
__global__ __launch_bounds__(256) void k_post(
    const float* __restrict__ P, const float* __restrict__ x,
    const float* __restrict__ num, const float* __restrict__ denB,
    const ushort* __restrict__ know16, const float* __restrict__ lng,
    const float* __restrict__ lnb, const float* __restrict__ C2w,
    const float* __restrict__ C2b, ushort* __restrict__ Afin)
{
  __shared__ __align__(16) ushort kbuf[32 * 512];
  __shared__ float attnL[4][64];
  __shared__ float w2L[4];
  int tid = threadIdx.x;
  int w = tid >> 6, lane = tid & 63;
  int r0 = blockIdx.x * 4;
  int r = r0 + w;
  size_t pr = (size_t)r * 1536;

  float h0 = P[pr + 1216 + lane], h1 = P[pr + 1280 + lane];
  float a0 = h0 * C2w[lane * 3 + 0] + h1 * C2w[(64 + lane) * 3 + 0];
  float a1 = h0 * C2w[lane * 3 + 1] + h1 * C2w[(64 + lane) * 3 + 1];
  float a2 = h0 * C2w[lane * 3 + 2] + h1 * C2w[(64 + lane) * 3 + 2];
  #pragma unroll
  for (int o = 32; o; o >>= 1) {
    a0 += __shfl_xor(a0, o); a1 += __shfl_xor(a1, o); a2 += __shfl_xor(a2, o);
  }
  a0 += C2b[0]; a1 += C2b[1]; a2 += C2b[2];
  float mxc = fmaxf(a0, fmaxf(a1, a2));
  float e0 = expf(a0 - mxc), e1 = expf(a1 - mxc), e2c = expf(a2 - mxc);
  float inv = 1.f / (e0 + e1 + e2c);
  float w0 = e0 * inv, w1 = e1 * inv, w2 = e2c * inv;
  if (lane == 0) w2L[w] = w2;

  {
    float dv = denB[r] + 1e-6f;
    float y[8];
    float4 n0 = *(const float4*)&num[(size_t)r * 512 + lane * 8];
    float4 n1 = *(const float4*)&num[(size_t)r * 512 + lane * 8 + 4];
    y[0] = n0.x / dv; y[1] = n0.y / dv; y[2] = n0.z / dv; y[3] = n0.w / dv;
    y[4] = n1.x / dv; y[5] = n1.y / dv; y[6] = n1.z / dv; y[7] = n1.w / dv;
    float s1 = 0.f, s2 = 0.f;
    #pragma unroll
    for (int i = 0; i < 8; ++i) { s1 += y[i]; s2 += y[i] * y[i]; }
    #pragma unroll
    for (int o = 32; o; o >>= 1) { s1 += __shfl_xor(s1, o); s2 += __shfl_xor(s2, o); }
    float mu = s1 * (1.f / 512.f);
    float var = s2 * (1.f / 512.f) - mu * mu;
    float rs = rsqrtf(var + 1e-5f);
    uint4 outv;
    uint pk[4];
    #pragma unroll
    for (int p2 = 0; p2 < 4; ++p2) {
      float o0 = (y[2 * p2] - mu) * rs * lng[lane * 8 + 2 * p2] + lnb[lane * 8 + 2 * p2];
      float o1 = (y[2 * p2 + 1] - mu) * rs * lng[lane * 8 + 2 * p2 + 1] + lnb[lane * 8 + 2 * p2 + 1];
      pk[p2] = (uint)f2b(o0 * w0) | ((uint)f2b(o1 * w0) << 16);
    }
    outv.x = pk[0]; outv.y = pk[1]; outv.z = pk[2]; outv.w = pk[3];
    *(uint4*)&Afin[(size_t)r * 1152 + lane * 8] = outv;
  }

  {
    int h = lane >> 4, ei = (lane & 15) * 2;
    float v0 = P[pr + 512 + h * 32 + ei], v1 = P[pr + 512 + h * 32 + ei + 1];
    float mxe = fmaxf(v0, v1);
    #pragma unroll
    for (int o = 1; o < 16; o <<= 1) mxe = fmaxf(mxe, __shfl_xor(mxe, o));
    float ee0 = __expf(v0 - mxe), ee1 = __expf(v1 - mxe);
    float ss = ee0 + ee1;
    #pragma unroll
    for (int o = 1; o < 16; o <<= 1) ss += __shfl_xor(ss, o);
    float sc1 = w1 / ss;
    uint pkv = (uint)f2b(ee0 * sc1) | ((uint)f2b(ee1 * sc1) << 16);
    *(uint*)&Afin[(size_t)r * 1152 + 1024 + h * 32 + ei] = pkv;
  }

  {
    float lv = P[pr + 640 + lane];
    float mx = lv;
    #pragma unroll
    for (int o = 32; o; o >>= 1) mx = fmaxf(mx, __shfl_xor(mx, o));
    float e = __expf(lv - mx);
    float sum = e;
    #pragma unroll
    for (int o = 32; o; o >>= 1) sum += __shfl_xor(sum, o);
    attnL[w][lane] = e / sum;
  }
  __syncthreads();

  int dd = tid * 2;
  float acc[4][2];
  #pragma unroll
  for (int i = 0; i < 4; ++i) { acc[i][0] = 0.f; acc[i][1] = 0.f; }
  for (int hs = 0; hs < 2; ++hs) {
    #pragma unroll
    for (int i = 0; i < 8; ++i) {
      int idx = i * 256 + tid;
      *(uint4*)&kbuf[idx * 8] = *(const uint4*)&know16[(size_t)hs * 16384 + idx * 8];
    }
    __syncthreads();
    for (int s = 0; s < 32; ++s) {
      uint uu = *(uint*)&kbuf[s * 512 + dd];
      float k0 = b2f((ushort)(uu & 0xffff));
      float k1 = b2f((ushort)(uu >> 16));
      #pragma unroll
      for (int row = 0; row < 4; ++row) {
        float a = attnL[row][hs * 32 + s];
        acc[row][0] += a * k0;
        acc[row][1] += a * k1;
      }
    }
    __syncthreads();
  }
  #pragma unroll
  for (int row = 0; row < 4; ++row) {
    int rr = r0 + row;
    float g0 = P[(size_t)rr * 1536 + 704 + dd];
    float g1 = P[(size_t)rr * 1536 + 704 + dd + 1];
    float x0 = x[(size_t)rr * 512 + dd], x1 = x[(size_t)rr * 512 + dd + 1];
    float w2v = w2L[row];
    float m0 = g0 * acc[row][0] + (1.f - g0) * x0;
    float m1 = g1 * acc[row][1] + (1.f - g1) * x1;
    uint pkv = (uint)f2b(w2v * m0) | ((uint)f2b(w2v * m1) << 16);
    *(uint*)&Afin[(size_t)rr * 1152 + 512 + dd] = pkv;
  }
}

// ---------- launch ----------
extern "C" void kernel_launch(void* const* d_in, const int* in_sizes, int n_in,
                              void* d_out, int out_size, void* d_ws, size_t ws_size,
                              hipStream_t stream)
{
  const float* x     = (const float*)d_in[0];
  const float* Wq    = (const float*)d_in[1];
  const float* Wk    = (const float*)d_in[2];
  const float* Wv    = (const float*)d_in[3];
  const float* Wf    = (const float*)d_in[4];
  const float* bfb   = (const float*)d_in[5];
  const float* Wo    = (const float*)d_in[6];
  const float* ln_g  = (const float*)d_in[7];
  const float* ln_b  = (const float*)d_in[8];
  const float* eslots= (const float*)d_in[9];
  const float* Eq    = (const float*)d_in[10];
  const float* Ek    = (const float*)d_in[11];
  const float* Ev    = (const float*)d_in[12];
  const float* Eo    = (const float*)d_in[13];
  const float* know  = (const float*)d_in[14];
  const float* Sin   = (const float*)d_in[15];
  const float* Sg_w  = (const float*)d_in[16];
  const float* Sg_b  = (const float*)d_in[17];
  const float* So    = (const float*)d_in[18];
  const float* C1w   = (const float*)d_in[19];
  const float* C1b   = (const float*)d_in[20];
  const float* C2w   = (const float*)d_in[21];
  const float* C2b   = (const float*)d_in[22];

  char* ws = (char*)d_ws;
  ushort* X16    = (ushort*)(ws + 0);
  ushort* Wcat   = (ushort*)(ws + 2097152);   // 1536 rows x 512 bf16
  ushort* Wfin   = (ushort*)(ws + 3670016);
  ushort* know16 = (ushort*)(ws + 4849664);
  float*  kh     = (float*)(ws + 4915200);    // 32 x 512 f32
  float*  vh     = (float*)(ws + 4980736);    // 32 x 512 f32
  float*  P      = (float*)(ws + 5046272);    // 2048 x 1536 f32
  float*  s16    = (float*)(ws + 18153472);   // 128 x 64 f32
  float*  zSend  = (float*)(ws + 18677760);   // 64 x 64 f32
  float*  den    = (float*)(ws + 19202048);   // 2048 f32
  float*  Send   = (float*)(ws + 19726336);   // 8.4 MB (32 chunks)
  float*  carry  = (float*)(ws + 28114944);   // 8.4 MB
  float*  num    = (float*)(ws + 36503552);   // 4.2 MB
  ushort* Afin   = (ushort*)(ws + 40697856);  // 4.7 MB

  k_prepA<<<dim3(384), dim3(256), 0, stream>>>(know, eslots, Ek, Ev, Sin, Wcat, kh, vh);
  k_prepB<<<dim3(952), dim3(256), 0, stream>>>(x, Wv, Sg_w, C1w, Wq, Wk, Wf, Wo, So,
                                               Eq, Eo, know, kh, vh,
                                               X16, Wcat, Wfin, know16);
  k_gemm1<<<dim3(12, 32), dim3(256), 0, stream>>>(X16, Wcat, P, Sg_b, C1b, bfb, s16);
  k_scanA<<<dim3(512), dim3(256), 0, stream>>>(P, s16, Send, zSend);
  k_scanB<<<dim3(256), dim3(256), 0, stream>>>(Send, carry);
  k_scanC<<<dim3(512), dim3(256), 0, stream>>>(P, s16, carry, zSend, num, den);
  k_post<<<dim3(512), dim3(256), 0, stream>>>(P, x, num, den, know16, ln_g, ln_b, C2w, C2b, Afin);
  k_gemm2<<<dim3(8, 32), dim3(256), 0, stream>>>(Afin, Wfin, (float*)d_out);
}

// Round 16
// 130.963 us; speedup vs baseline: 1.1565x; 1.1565x over previous
//
#include <hip/hip_runtime.h>
#include <cstdint>

typedef unsigned int uint;
typedef unsigned short ushort;
typedef __attribute__((ext_vector_type(8))) short bf16x8;
typedef __attribute__((ext_vector_type(4))) float f32x4;

// ---------- helpers ----------
__device__ __forceinline__ ushort f2b(float f) {
  union { float f; uint u; } v; v.f = f;
  uint u = v.u;
  uint r = (u + 0x7FFFu + ((u >> 16) & 1u)) >> 16;   // RNE
  return (ushort)r;
}
__device__ __forceinline__ float b2f(ushort h) {
  union { uint u; float f; } v; v.u = ((uint)h) << 16; return v.f;
}

// ---------- K_prepA: SK (blocks 0..255) + kh/vh (blocks 256..383); no LDS ----------
__global__ __launch_bounds__(256) void k_prepA(
    const float* __restrict__ know, const float* __restrict__ eslots,
    const float* __restrict__ Ek, const float* __restrict__ Ev, const float* __restrict__ Sin,
    ushort* __restrict__ Wcat, float* __restrict__ kh, float* __restrict__ vh)
{
  int bid = blockIdx.x;
  int tid = threadIdx.x;
  int lane = tid & 63, wv = tid >> 6;

  if (bid < 256) {
    int k = bid * 2 + (wv >> 1);         // [0,512)
    int s0 = (wv & 1) * 32;
    const float* sp = Sin + (size_t)k * 512 + lane * 8;
    float4 s1 = *(const float4*)&sp[0];
    float4 s2 = *(const float4*)&sp[4];
    #pragma unroll 4
    for (int si = 0; si < 32; ++si) {
      int s = s0 + si;
      const float* kp = know + (size_t)s * 512 + lane * 8;
      float4 k1 = *(const float4*)&kp[0];
      float4 k2 = *(const float4*)&kp[4];
      float part = s1.x * k1.x + s1.y * k1.y + s1.z * k1.z + s1.w * k1.w
                 + s2.x * k2.x + s2.y * k2.y + s2.z * k2.z + s2.w * k2.w;
      #pragma unroll
      for (int o = 32; o; o >>= 1) part += __shfl_xor(part, o);
      if (lane == 0) Wcat[(640 + s) * 512 + k] = f2b(part * 0.04419417382415922f); // 1/sqrt(512)
    }
    return;
  }
  {
    int t = (bid - 256) * 256 + tid;     // [0,32768)
    int isv = (t >= 16384);
    int o = t & 16383; int s = o >> 9, j = o & 511;
    const float* W = isv ? Ev : Ek;
    const float* es = eslots + (size_t)s * 512;
    float a0 = 0.f, a1 = 0.f, a2 = 0.f, a3 = 0.f;
    #pragma unroll 8
    for (int d = 0; d < 512; d += 4) {
      a0 += es[d + 0] * W[(size_t)(d + 0) * 512 + j];
      a1 += es[d + 1] * W[(size_t)(d + 1) * 512 + j];
      a2 += es[d + 2] * W[(size_t)(d + 2) * 512 + j];
      a3 += es[d + 3] * W[(size_t)(d + 3) * 512 + j];
    }
    float acc = (a0 + a1) + (a2 + a3);
    (isv ? vh : kh)[(size_t)s * 512 + j] = acc;
  }
}

// ---------- K_prepB: EK (0..255) + VO (256..511) + transposes (512..807) + X16 (808..935) + know16 (936..951) ----------
__global__ __launch_bounds__(256) void k_prepB(
    const float* __restrict__ x, const float* __restrict__ Wv, const float* __restrict__ Sg,
    const float* __restrict__ C1w, const float* __restrict__ Wq, const float* __restrict__ Wk,
    const float* __restrict__ Wf, const float* __restrict__ Wo, const float* __restrict__ So,
    const float* __restrict__ Eq, const float* __restrict__ Eo, const float* __restrict__ know,
    const float* __restrict__ kh, const float* __restrict__ vh,
    ushort* __restrict__ X16, ushort* __restrict__ Wcat, ushort* __restrict__ Wfin,
    ushort* __restrict__ know16)
{
  __shared__ __align__(16) float pool[4160];
  int bid = blockIdx.x;
  int tid = threadIdx.x;
  int lane = tid & 63, wv = tid >> 6;

  if (bid < 256) {
    int gw = bid * 4 + wv;               // [0,1024)
    #pragma unroll
    for (int pp = 0; pp < 2; ++pp) {
      int pair = gw * 2 + pp;            // [0,2048) = (k,h)
      int k = pair >> 2, h = pair & 3;
      const float* ep = Eq + (size_t)k * 512 + h * 128 + lane * 2;
      float e0 = ep[0], e1 = ep[1];
      #pragma unroll 4
      for (int s = 0; s < 32; ++s) {
        const float* kp = kh + (size_t)s * 512 + h * 128 + lane * 2;
        float part = e0 * kp[0] + e1 * kp[1];
        #pragma unroll
        for (int o = 32; o; o >>= 1) part += __shfl_xor(part, o);
        if (lane == 0) Wcat[(512 + h * 32 + s) * 512 + k] = f2b(part * 0.08838834764831845f);
      }
    }
    return;
  }
  if (bid < 512) {
    int o = (bid - 256) * 256 + tid;     // [0,65536)
    int hs = o >> 9, j = o & 511;
    int h = hs >> 5, s = hs & 31;
    const float* vhp = vh + (size_t)s * 512 + h * 128;
    float acc = 0.f;
    #pragma unroll 16
    for (int e = 0; e < 128; ++e) acc += vhp[e] * Eo[(size_t)(h * 128 + e) * 512 + j];
    Wfin[(size_t)j * 1152 + 1024 + hs] = f2b(acc);
    return;
  }
  if (bid < 808) {
    #define Tm(a,b) pool[(a) * 65 + (b)]
    int tt = bid - 512;
    const float* src; ushort* dst; int sld, dld, Nt, drow, dcol;
    if (tt < 64)       {           src = Wv;  dst = Wcat; sld = 512; dld = 512;  Nt = 8; drow = 0;    dcol = 0;   }
    else if (tt < 128) { tt -= 64; src = Sg;  dst = Wcat; sld = 512; dld = 512;  Nt = 8; drow = 704;  dcol = 0;   }
    else if (tt < 144) { tt -= 128; src = C1w; dst = Wcat; sld = 128; dld = 512; Nt = 2; drow = 1216; dcol = 0;   }
    else if (tt < 152) { tt -= 144; src = Wq;  dst = Wcat; sld = 64;  dld = 512; Nt = 1; drow = 1344; dcol = 0;   }
    else if (tt < 160) { tt -= 152; src = Wk;  dst = Wcat; sld = 64;  dld = 512; Nt = 1; drow = 1408; dcol = 0;   }
    else if (tt < 168) { tt -= 160; src = Wf;  dst = Wcat; sld = 64;  dld = 512; Nt = 1; drow = 1472; dcol = 0;   }
    else if (tt < 232) { tt -= 168; src = Wo;  dst = Wfin; sld = 512; dld = 1152; Nt = 8; drow = 0;   dcol = 0;   }
    else               { tt -= 232; src = So;  dst = Wfin; sld = 512; dld = 1152; Nt = 8; drow = 0;   dcol = 512; }
    int tk = tt / Nt, tn = tt % Nt;
    int k0 = tk * 64, n0 = tn * 64;
    int r = tid >> 4, c = (tid & 15) * 4;
    #pragma unroll
    for (int p = 0; p < 4; ++p) {
      int kk = p * 16 + r;
      float4 v = *(const float4*)&src[(size_t)(k0 + kk) * sld + n0 + c];
      Tm(c + 0, kk) = v.x; Tm(c + 1, kk) = v.y; Tm(c + 2, kk) = v.z; Tm(c + 3, kk) = v.w;
    }
    __syncthreads();
    int n = tid >> 2, kc = (tid & 3) * 16;
    uint u[8];
    #pragma unroll
    for (int j = 0; j < 8; ++j) {
      ushort lo = f2b(Tm(n, kc + 2 * j));
      ushort hi = f2b(Tm(n, kc + 2 * j + 1));
      u[j] = (uint)lo | ((uint)hi << 16);
    }
    size_t off = (size_t)(drow + n0 + n) * dld + dcol + k0 + kc;
    uint4 o1; o1.x = u[0]; o1.y = u[1]; o1.z = u[2]; o1.w = u[3];
    uint4 o2; o2.x = u[4]; o2.y = u[5]; o2.z = u[6]; o2.w = u[7];
    *(uint4*)&dst[off] = o1;
    *(uint4*)&dst[off + 8] = o2;
    #undef Tm
    return;
  }
  if (bid < 936) {
    int base = (bid - 808) * 256 + tid;
    #pragma unroll
    for (int it = 0; it < 8; ++it) {
      int t = base + it * 32768;
      float4 xv = *(const float4*)&x[(size_t)t * 4];
      uint2 o;
      o.x = (uint)f2b(xv.x) | ((uint)f2b(xv.y) << 16);
      o.y = (uint)f2b(xv.z) | ((uint)f2b(xv.w) << 16);
      *(uint2*)&X16[(size_t)t * 4] = o;
    }
    return;
  }
  {
    int t = (bid - 936) * 256 + tid;
    #pragma unroll
    for (int j = 0; j < 2; ++j) {
      float4 v = *(const float4*)&know[(size_t)t * 8 + j * 4];
      uint2 o;
      o.x = (uint)f2b(v.x) | ((uint)f2b(v.y) << 16);
      o.y = (uint)f2b(v.z) | ((uint)f2b(v.w) << 16);
      *(uint2*)&know16[(size_t)t * 8 + j * 4] = o;
    }
  }
}

// ---------- GEMM1: 64x128 tile, X16(2048x512) @ Wcat^T -> P(2048x1536), fused epilogues ----------
__global__ __launch_bounds__(256) void k_gemm1(
    const ushort* __restrict__ A, const ushort* __restrict__ Bw, float* __restrict__ C,
    const float* __restrict__ sgb, const float* __restrict__ c1b, const float* __restrict__ bfb)
{
  __shared__ __align__(16) ushort As[64 * 32];
  __shared__ __align__(16) ushort Bs[128 * 32];
  int tid = threadIdx.x;
  int lane = tid & 63, wv = tid >> 6;
  int wm = (wv & 1) * 32, wn = (wv >> 1) * 64;
  int lr = lane & 15, lk = lane >> 4;
  int m0 = blockIdx.y * 64, n0 = blockIdx.x * 128;
  f32x4 zero4 = {0.f, 0.f, 0.f, 0.f};
  f32x4 acc[2][4];
  #pragma unroll
  for (int a = 0; a < 2; ++a)
    #pragma unroll
    for (int b = 0; b < 4; ++b) acc[a][b] = zero4;
  for (int kt = 0; kt < 16; ++kt) {
    int k0 = kt * 32;
    {
      int p = tid, row = p >> 2, cc = p & 3;
      int cs = cc ^ ((row >> 1) & 3);
      *(uint4*)&As[p * 8] = *(const uint4*)&A[(size_t)(m0 + row) * 512 + k0 + cs * 8];
    }
    #pragma unroll
    for (int i = 0; i < 2; ++i) {
      int p = i * 256 + tid, row = p >> 2, cc = p & 3;
      int cs = cc ^ ((row >> 1) & 3);
      *(uint4*)&Bs[p * 8] = *(const uint4*)&Bw[(size_t)(n0 + row) * 512 + k0 + cs * 8];
    }
    __syncthreads();
    bf16x8 af[2], bfv[4];
    #pragma unroll
    for (int mi = 0; mi < 2; ++mi) {
      int row = wm + mi * 16 + lr;
      int cc = lk ^ ((row >> 1) & 3);
      af[mi] = *(bf16x8*)&As[row * 32 + cc * 8];
    }
    #pragma unroll
    for (int ni = 0; ni < 4; ++ni) {
      int row = wn + ni * 16 + lr;
      int cc = lk ^ ((row >> 1) & 3);
      bfv[ni] = *(bf16x8*)&Bs[row * 32 + cc * 8];
    }
    #pragma unroll
    for (int mi = 0; mi < 2; ++mi)
      #pragma unroll
      for (int ni = 0; ni < 4; ++ni)
        acc[mi][ni] = __builtin_amdgcn_mfma_f32_16x16x32_bf16(af[mi], bfv[ni], acc[mi][ni], 0, 0, 0);
    __syncthreads();
  }
  #pragma unroll
  for (int mi = 0; mi < 2; ++mi) {
    #pragma unroll
    for (int ni = 0; ni < 4; ++ni) {
      int col = n0 + wn + ni * 16 + lr;
      #pragma unroll
      for (int r = 0; r < 4; ++r) {
        int rowb = m0 + wm + mi * 16 + lk * 4 + r;
        float v = acc[mi][ni][r];
        if (col >= 704) {
          if (col < 1216) { v = 1.f / (1.f + __expf(-(v + sgb[col - 704]))); }            // sigmoid gate
          else if (col < 1344) { float tt = v + c1b[col - 1216]; v = tt / (1.f + __expf(-tt)); } // silu
          else if (col < 1408) { float e = (v > 0.f) ? v : (__expf(v) - 1.f); v = (e + 1.f) * 0.125f; } // q
          else if (col < 1472) { float e = (v > 0.f) ? v : (__expf(v) - 1.f); v = e + 1.f; }            // k
          else { float logit = v + bfb[col - 1472];
                 float s = 1.f / (1.f + expf(-logit));
                 v = logf(fmaxf(s, 1e-6f)); }                                             // log forget
        }
        C[(size_t)rowb * 1536 + col] = v;
      }
    }
  }
}

// ---------- GEMM2: 64x64 tile, Afin(2048x1152) @ Wfin^T -> out(2048x512) ----------
__global__ __launch_bounds__(256) void k_gemm2(
    const ushort* __restrict__ A, const ushort* __restrict__ Bw, float* __restrict__ C)
{
  __shared__ __align__(16) ushort As[64 * 32];
  __shared__ __align__(16) ushort Bs[64 * 32];
  int tid = threadIdx.x;
  int lane = tid & 63, wv = tid >> 6;
  int wm = (wv & 1) * 32, wn = (wv >> 1) * 32;
  int lr = lane & 15, lk = lane >> 4;
  int m0 = blockIdx.y * 64, n0 = blockIdx.x * 64;
  f32x4 zero4 = {0.f, 0.f, 0.f, 0.f};
  f32x4 acc[2][2];
  #pragma unroll
  for (int a = 0; a < 2; ++a)
    #pragma unroll
    for (int b = 0; b < 2; ++b) acc[a][b] = zero4;
  for (int kt = 0; kt < 36; ++kt) {
    int k0 = kt * 32;
    {
      int p = tid, row = p >> 2, cc = p & 3;
      int cs = cc ^ ((row >> 1) & 3);
      *(uint4*)&As[p * 8] = *(const uint4*)&A[(size_t)(m0 + row) * 1152 + k0 + cs * 8];
      *(uint4*)&Bs[p * 8] = *(const uint4*)&Bw[(size_t)(n0 + row) * 1152 + k0 + cs * 8];
    }
    __syncthreads();
    bf16x8 af[2], bfv[2];
    #pragma unroll
    for (int mi = 0; mi < 2; ++mi) {
      int row = wm + mi * 16 + lr;
      int cc = lk ^ ((row >> 1) & 3);
      af[mi] = *(bf16x8*)&As[row * 32 + cc * 8];
    }
    #pragma unroll
    for (int ni = 0; ni < 2; ++ni) {
      int row = wn + ni * 16 + lr;
      int cc = lk ^ ((row >> 1) & 3);
      bfv[ni] = *(bf16x8*)&Bs[row * 32 + cc * 8];
    }
    #pragma unroll
    for (int mi = 0; mi < 2; ++mi)
      #pragma unroll
      for (int ni = 0; ni < 2; ++ni)
        acc[mi][ni] = __builtin_amdgcn_mfma_f32_16x16x32_bf16(af[mi], bfv[ni], acc[mi][ni], 0, 0, 0);
    __syncthreads();
  }
  #pragma unroll
  for (int mi = 0; mi < 2; ++mi) {
    #pragma unroll
    for (int ni = 0; ni < 2; ++ni) {
      int col = n0 + wn + ni * 16 + lr;
      #pragma unroll
      for (int r = 0; r < 4; ++r) {
        int rowb = m0 + wm + mi * 16 + lk * 4 + r;
        C[(size_t)rowb * 512 + col] = acc[mi][ni][r];
      }
    }
  }
}

// ---------- K_gate: gatescan only (128 blocks), logf from P col 1472 ----------
__global__ __launch_bounds__(256) void k_gate(
    const float* __restrict__ P,
    float* __restrict__ cn, float* __restrict__ qe, float* __restrict__ qz)
{
  __shared__ float wsumA[4];
  __shared__ float wsumB[4];
  int bid = blockIdx.x;
  int tid = threadIdx.x;
  int b = bid >> 6, m = bid & 63;
  int lane = tid & 63, wv = tid >> 6;
  size_t rbase = (size_t)b * 1024 + tid * 4;

  float v0 = P[(rbase + 0) * 1536 + 1472 + m];
  float v1 = P[(rbase + 1) * 1536 + 1472 + m];
  float v2 = P[(rbase + 2) * 1536 + 1472 + m];
  float v3 = P[(rbase + 3) * 1536 + 1472 + m];
  v1 += v0; v2 += v1; v3 += v2;
  float tsum = v3;
  float sc = tsum;
  #pragma unroll
  for (int o = 1; o < 64; o <<= 1) {
    float t = __shfl_up(sc, o, 64);
    if (lane >= o) sc += t;
  }
  if (lane == 63) wsumA[wv] = sc;
  __syncthreads();
  float excl = sc - tsum;
  #pragma unroll
  for (int w2 = 0; w2 < 3; ++w2) if (w2 < wv) excl += wsumA[w2];

  float vv[4] = {v0, v1, v2, v3};
  float cv[4], qv[4];
  #pragma unroll
  for (int i = 0; i < 4; ++i) {
    size_t r = rbase + i;
    float lf = fminf(fmaxf(excl + vv[i], -20.f), 20.f);
    float en = expf(-lf), ep = expf(lf);
    float kk = P[r * 1536 + 1408 + m];
    float qq = P[r * 1536 + 1344 + m];
    cv[i] = en * kk;
    qv[i] = qq * ep;
    cn[r * 64 + m] = cv[i];
    qe[r * 64 + m] = qv[i];
  }

  float c1 = cv[0], c2 = c1 + cv[1], c3 = c2 + cv[2], c4 = c3 + cv[3];
  float t2 = c4;
  float sc2 = t2;
  #pragma unroll
  for (int o = 1; o < 64; o <<= 1) {
    float t = __shfl_up(sc2, o, 64);
    if (lane >= o) sc2 += t;
  }
  if (lane == 63) wsumB[wv] = sc2;
  __syncthreads();
  float excl2 = sc2 - t2;
  #pragma unroll
  for (int w2 = 0; w2 < 3; ++w2) if (w2 < wv) excl2 += wsumB[w2];

  float pr[4] = {c1, c2, c3, c4};
  #pragma unroll
  for (int i = 0; i < 4; ++i) {
    size_t r = rbase + i;
    qz[r * 64 + m] = qv[i] * (excl2 + pr[i]);
  }
}

// ---------- K_scanA: per-chunk partial states, 32 chunks of 32 rows ----------
__global__ __launch_bounds__(256) void k_scanA(
    const float* __restrict__ cn, const float* __restrict__ P, float* __restrict__ Send)
{
  __shared__ __align__(16) float cnS[32 * 64];
  __shared__ __align__(16) float vS[16 * 64];
  int tid = threadIdx.x;
  int bid = blockIdx.x;
  int dt = bid & 7, c = (bid >> 3) & 31, b = bid >> 8;
  int rb0 = b * 1024 + c * 32;
  #pragma unroll
  for (int it = 0; it < 2; ++it) {
    int p = it * 256 + tid;
    int row = p >> 4, c4f = (p & 15) * 4;
    *(float4*)&cnS[row * 64 + c4f] = *(const float4*)&cn[(size_t)(rb0 + row) * 64 + c4f];
  }
  __syncthreads();
  int mg = tid >> 4, dl = tid & 15;
  float4 acc[4];
  #pragma unroll
  for (int i = 0; i < 4; ++i) acc[i] = make_float4(0.f, 0.f, 0.f, 0.f);
  for (int ig = 0; ig < 2; ++ig) {
    int rb = rb0 + ig * 16;
    int row = tid >> 4, c4f = (tid & 15) * 4;
    *(float4*)&vS[row * 64 + c4f] = *(const float4*)&P[(size_t)(rb + row) * 1536 + dt * 64 + c4f];
    __syncthreads();
    #pragma unroll 4
    for (int i = 0; i < 16; ++i) {
      float4 vv = *(float4*)&vS[i * 64 + dl * 4];
      float4 cm = *(float4*)&cnS[(ig * 16 + i) * 64 + mg * 4];
      acc[0].x += cm.x * vv.x; acc[0].y += cm.x * vv.y; acc[0].z += cm.x * vv.z; acc[0].w += cm.x * vv.w;
      acc[1].x += cm.y * vv.x; acc[1].y += cm.y * vv.y; acc[1].z += cm.y * vv.z; acc[1].w += cm.y * vv.w;
      acc[2].x += cm.z * vv.x; acc[2].y += cm.z * vv.y; acc[2].z += cm.z * vv.z; acc[2].w += cm.z * vv.w;
      acc[3].x += cm.w * vv.x; acc[3].y += cm.w * vv.y; acc[3].z += cm.w * vv.z; acc[3].w += cm.w * vv.w;
    }
    __syncthreads();
  }
  #pragma unroll
  for (int mi = 0; mi < 4; ++mi) {
    int m = mg * 4 + mi;
    *(float4*)&Send[(size_t)((b * 32 + c) * 64 + m) * 512 + dt * 64 + dl * 4] = acc[mi];
  }
}

// ---------- K_scanB: exclusive chunk prefix over 32 chunks ----------
__global__ __launch_bounds__(256) void k_scanB(const float* __restrict__ Send, float* __restrict__ carry)
{
  int t = blockIdx.x * 256 + threadIdx.x;   // 65536
  int d = t & 511, m = (t >> 9) & 63, b = t >> 15;
  float run = 0.f;
  #pragma unroll 8
  for (int c = 0; c < 32; ++c) {
    size_t idx = (size_t)((b * 32 + c) * 64 + m) * 512 + d;
    carry[idx] = run;
    run += Send[idx];
  }
}

// ---------- K_scanC: in-chunk sequential scan -> num (32 chunks of 32 rows) ----------
__global__ __launch_bounds__(256) void k_scanC(
    const float* __restrict__ cn, const float* __restrict__ qe, const float* __restrict__ P,
    const float* __restrict__ carry, float* __restrict__ num)
{
  __shared__ __align__(16) float cnS[32 * 64];
  __shared__ __align__(16) float qeS[32 * 64];
  __shared__ __align__(16) float vS[16 * 64];
  int tid = threadIdx.x;
  int bid = blockIdx.x;
  int dt = bid & 7, c = (bid >> 3) & 31, b = bid >> 8;
  int rb0 = b * 1024 + c * 32;
  #pragma unroll
  for (int it = 0; it < 2; ++it) {
    int p = it * 256 + tid;
    int row = p >> 4, c4f = (p & 15) * 4;
    *(float4*)&cnS[row * 64 + c4f] = *(const float4*)&cn[(size_t)(rb0 + row) * 64 + c4f];
    *(float4*)&qeS[row * 64 + c4f] = *(const float4*)&qe[(size_t)(rb0 + row) * 64 + c4f];
  }
  int mg = tid & 3, dl = tid >> 2;
  int d = dt * 64 + dl;
  float S[16];
  #pragma unroll
  for (int mi = 0; mi < 16; ++mi)
    S[mi] = carry[(size_t)((b * 32 + c) * 64 + mg * 16 + mi) * 512 + d];
  __syncthreads();
  for (int ig = 0; ig < 2; ++ig) {
    int rb = rb0 + ig * 16;
    int row = tid >> 4, c4f = (tid & 15) * 4;
    *(float4*)&vS[row * 64 + c4f] = *(const float4*)&P[(size_t)(rb + row) * 1536 + dt * 64 + c4f];
    __syncthreads();
    for (int i = 0; i < 16; ++i) {
      int ii = ig * 16 + i;
      float vv = vS[i * 64 + dl];
      float p = 0.f;
      #pragma unroll
      for (int j = 0; j < 4; ++j) {
        float4 c4 = *(float4*)&cnS[ii * 64 + mg * 16 + j * 4];
        float4 q4 = *(float4*)&qeS[ii * 64 + mg * 16 + j * 4];
        S[j * 4 + 0] += c4.x * vv; p += q4.x * S[j * 4 + 0];
        S[j * 4 + 1] += c4.y * vv; p += q4.y * S[j * 4 + 1];
        S[j * 4 + 2] += c4.z * vv; p += q4.z * S[j * 4 + 2];
        S[j * 4 + 3] += c4.w * vv; p += q4.w * S[j * 4 + 3];
      }
      p += __shfl_xor(p, 1);
      p += __shfl_xor(p, 2);
      if (mg == 0) num[(size_t)(rb0 + ii) * 512 + d] = p;
    }
    __syncthreads();
  }
}

// ---------- K_post: ctrl + ln + esoft + sem fused (4 rows/block, wave=row) ----------
__global__ __launch_bounds__(256) void k_post(
    const float* __restrict__ P, const float* __restrict__ x,
    const float* __restrict__ num, const float* __restrict__ qz,
    const ushort* __restrict__ know16, const float* __restrict__ lng,
    const float* __restrict__ lnb, const float* __restrict__ C2w,
    const float* __restrict__ C2b, ushort* __restrict__ Afin)
{
  __shared__ __align__(16) ushort kbuf[32 * 512];
  __shared__ float attnL[4][64];
  __shared__ float w2L[4];
  int tid = threadIdx.x;
  int w = tid >> 6, lane = tid & 63;
  int r0 = blockIdx.x * 4;
  int r = r0 + w;
  size_t pr = (size_t)r * 1536;

  float h0 = P[pr + 1216 + lane], h1 = P[pr + 1280 + lane];
  float a0 = h0 * C2w[lane * 3 + 0] + h1 * C2w[(64 + lane) * 3 + 0];
  float a1 = h0 * C2w[lane * 3 + 1] + h1 * C2w[(64 + lane) * 3 + 1];
  float a2 = h0 * C2w[lane * 3 + 2] + h1 * C2w[(64 + lane) * 3 + 2];
  #pragma unroll
  for (int o = 32; o; o >>= 1) {
    a0 += __shfl_xor(a0, o); a1 += __shfl_xor(a1, o); a2 += __shfl_xor(a2, o);
  }
  a0 += C2b[0]; a1 += C2b[1]; a2 += C2b[2];
  float mxc = fmaxf(a0, fmaxf(a1, a2));
  float e0 = expf(a0 - mxc), e1 = expf(a1 - mxc), e2c = expf(a2 - mxc);
  float inv = 1.f / (e0 + e1 + e2c);
  float w0 = e0 * inv, w1 = e1 * inv, w2 = e2c * inv;
  if (lane == 0) w2L[w] = w2;

  {
    float den = qz[(size_t)r * 64 + lane];
    #pragma unroll
    for (int o = 32; o; o >>= 1) den += __shfl_xor(den, o);
    den += 1e-6f;
    float y[8];
    float4 n0 = *(const float4*)&num[(size_t)r * 512 + lane * 8];
    float4 n1 = *(const float4*)&num[(size_t)r * 512 + lane * 8 + 4];
    y[0] = n0.x / den; y[1] = n0.y / den; y[2] = n0.z / den; y[3] = n0.w / den;
    y[4] = n1.x / den; y[5] = n1.y / den; y[6] = n1.z / den; y[7] = n1.w / den;
    float s1 = 0.f, s2 = 0.f;
    #pragma unroll
    for (int i = 0; i < 8; ++i) { s1 += y[i]; s2 += y[i] * y[i]; }
    #pragma unroll
    for (int o = 32; o; o >>= 1) { s1 += __shfl_xor(s1, o); s2 += __shfl_xor(s2, o); }
    float mu = s1 * (1.f / 512.f);
    float var = s2 * (1.f / 512.f) - mu * mu;
    float rs = rsqrtf(var + 1e-5f);
    uint4 outv;
    uint pk[4];
    #pragma unroll
    for (int p2 = 0; p2 < 4; ++p2) {
      float o0 = (y[2 * p2] - mu) * rs * lng[lane * 8 + 2 * p2] + lnb[lane * 8 + 2 * p2];
      float o1 = (y[2 * p2 + 1] - mu) * rs * lng[lane * 8 + 2 * p2 + 1] + lnb[lane * 8 + 2 * p2 + 1];
      pk[p2] = (uint)f2b(o0 * w0) | ((uint)f2b(o1 * w0) << 16);
    }
    outv.x = pk[0]; outv.y = pk[1]; outv.z = pk[2]; outv.w = pk[3];
    *(uint4*)&Afin[(size_t)r * 1152 + lane * 8] = outv;
  }

  {
    int h = lane >> 4, ei = (lane & 15) * 2;
    float v0 = P[pr + 512 + h * 32 + ei], v1 = P[pr + 512 + h * 32 + ei + 1];
    float mxe = fmaxf(v0, v1);
    #pragma unroll
    for (int o = 1; o < 16; o <<= 1) mxe = fmaxf(mxe, __shfl_xor(mxe, o));
    float ee0 = __expf(v0 - mxe), ee1 = __expf(v1 - mxe);
    float ss = ee0 + ee1;
    #pragma unroll
    for (int o = 1; o < 16; o <<= 1) ss += __shfl_xor(ss, o);
    float sc1 = w1 / ss;
    uint pkv = (uint)f2b(ee0 * sc1) | ((uint)f2b(ee1 * sc1) << 16);
    *(uint*)&Afin[(size_t)r * 1152 + 1024 + h * 32 + ei] = pkv;
  }

  {
    float lv = P[pr + 640 + lane];
    float mx = lv;
    #pragma unroll
    for (int o = 32; o; o >>= 1) mx = fmaxf(mx, __shfl_xor(mx, o));
    float e = __expf(lv - mx);
    float sum = e;
    #pragma unroll
    for (int o = 32; o; o >>= 1) sum += __shfl_xor(sum, o);
    attnL[w][lane] = e / sum;
  }
  __syncthreads();

  int dd = tid * 2;
  float acc[4][2];
  #pragma unroll
  for (int i = 0; i < 4; ++i) { acc[i][0] = 0.f; acc[i][1] = 0.f; }
  for (int hs = 0; hs < 2; ++hs) {
    #pragma unroll
    for (int i = 0; i < 8; ++i) {
      int idx = i * 256 + tid;
      *(uint4*)&kbuf[idx * 8] = *(const uint4*)&know16[(size_t)hs * 16384 + idx * 8];
    }
    __syncthreads();
    for (int s = 0; s < 32; ++s) {
      uint uu = *(uint*)&kbuf[s * 512 + dd];
      float k0 = b2f((ushort)(uu & 0xffff));
      float k1 = b2f((ushort)(uu >> 16));
      #pragma unroll
      for (int row = 0; row < 4; ++row) {
        float a = attnL[row][hs * 32 + s];
        acc[row][0] += a * k0;
        acc[row][1] += a * k1;
      }
    }
    __syncthreads();
  }
  #pragma unroll
  for (int row = 0; row < 4; ++row) {
    int rr = r0 + row;
    float g0 = P[(size_t)rr * 1536 + 704 + dd];
    float g1 = P[(size_t)rr * 1536 + 704 + dd + 1];
    float x0 = x[(size_t)rr * 512 + dd], x1 = x[(size_t)rr * 512 + dd + 1];
    float w2v = w2L[row];
    float m0 = g0 * acc[row][0] + (1.f - g0) * x0;
    float m1 = g1 * acc[row][1] + (1.f - g1) * x1;
    uint pkv = (uint)f2b(w2v * m0) | ((uint)f2b(w2v * m1) << 16);
    *(uint*)&Afin[(size_t)rr * 1152 + 512 + dd] = pkv;
  }
}

// ---------- launch ----------
extern "C" void kernel_launch(void* const* d_in, const int* in_sizes, int n_in,
                              void* d_out, int out_size, void* d_ws, size_t ws_size,
                              hipStream_t stream)
{
  const float* x     = (const float*)d_in[0];
  const float* Wq    = (const float*)d_in[1];
  const float* Wk    = (const float*)d_in[2];
  const float* Wv    = (const float*)d_in[3];
  const float* Wf    = (const float*)d_in[4];
  const float* bfb   = (const float*)d_in[5];
  const float* Wo    = (const float*)d_in[6];
  const float* ln_g  = (const float*)d_in[7];
  const float* ln_b  = (const float*)d_in[8];
  const float* eslots= (const float*)d_in[9];
  const float* Eq    = (const float*)d_in[10];
  const float* Ek    = (const float*)d_in[11];
  const float* Ev    = (const float*)d_in[12];
  const float* Eo    = (const float*)d_in[13];
  const float* know  = (const float*)d_in[14];
  const float* Sin   = (const float*)d_in[15];
  const float* Sg_w  = (const float*)d_in[16];
  const float* Sg_b  = (const float*)d_in[17];
  const float* So    = (const float*)d_in[18];
  const float* C1w   = (const float*)d_in[19];
  const float* C1b   = (const float*)d_in[20];
  const float* C2w   = (const float*)d_in[21];
  const float* C2b   = (const float*)d_in[22];

  char* ws = (char*)d_ws;
  ushort* X16    = (ushort*)(ws + 0);
  ushort* Wcat   = (ushort*)(ws + 2097152);   // 1536 rows x 512 bf16
  ushort* Wfin   = (ushort*)(ws + 3670016);
  ushort* know16 = (ushort*)(ws + 4849664);
  float*  kh     = (float*)(ws + 4915200);    // 32 x 512 f32
  float*  vh     = (float*)(ws + 4980736);    // 32 x 512 f32
  float*  P      = (float*)(ws + 5046272);    // 2048 x 1536 f32
  float*  cn     = (float*)(ws + 18153472);
  float*  qe     = (float*)(ws + 18677760);
  float*  qz     = (float*)(ws + 19202048);
  float*  Send   = (float*)(ws + 19726336);   // 8.4 MB (32 chunks)
  float*  carry  = (float*)(ws + 28114944);   // 8.4 MB
  float*  num    = (float*)(ws + 36503552);   // 4.2 MB
  ushort* Afin   = (ushort*)(ws + 40697856);  // 4.7 MB

  k_prepA<<<dim3(384), dim3(256), 0, stream>>>(know, eslots, Ek, Ev, Sin, Wcat, kh, vh);
  k_prepB<<<dim3(952), dim3(256), 0, stream>>>(x, Wv, Sg_w, C1w, Wq, Wk, Wf, Wo, So,
                                               Eq, Eo, know, kh, vh,
                                               X16, Wcat, Wfin, know16);
  k_gemm1<<<dim3(12, 32), dim3(256), 0, stream>>>(X16, Wcat, P, Sg_b, C1b, bfb);
  k_gate<<<dim3(128), dim3(256), 0, stream>>>(P, cn, qe, qz);
  k_scanA<<<dim3(512), dim3(256), 0, stream>>>(cn, P, Send);
  k_scanB<<<dim3(256), dim3(256), 0, stream>>>(Send, carry);
  k_scanC<<<dim3(512), dim3(256), 0, stream>>>(cn, qe, P, carry, num);
  k_post<<<dim3(512), dim3(256), 0, stream>>>(P, x, num, qz, know16, ln_g, ln_b, C2w, C2b, Afin);
  k_gemm2<<<dim3(8, 32), dim3(256), 0, stream>>>(Afin, Wfin, (float*)d_out);
}